// Round 10
// baseline (18.971 us; speedup 1.0000x reference)
//
#include <hip/hip_runtime.h>
#include <hip/hip_fp16.h>

#define N_PART 512
#define H_DIM 32
#define M_DIM 4
#define L_DIM 8
#define N_STEPS (M_DIM * (L_DIM - 1))   // 28
#define N_JOBS (N_STEPS + M_DIM)        // 32
#define NBLK (N_JOBS * 32)              // 1024 (32 rowgroups of 16 rows)
#define NCELL 2048
#define RMAX 10.0f
#define TSCALE ((float)NCELL / RMAX)    // 204.8
#define TWO_LOG2E 2.8853900817779268f

// ws layout (two 4B-stride planes -> full 32-bank spread on random gathers;
// round-3 lesson: 8B-stride pairs alias to even banks):
//  [0, 8KB)     stTab  float[2048]     St (f32 — feeds telescoped E)
//  [8K, 16KB)   gsTab  uint[2048]      packed {Sg,Sl} as 2xf16
//  [16K, 40KB)  partials double[1024][3]
#define ST_OFF 0
#define GS_OFF (NCELL * 4)
#define PART_OFF (NCELL * 8)

// ---------------------------------------------------------------------------
// DPP-based 32-lane sum reduction (round-8 win: reduce on VALU pipe, not the
// contended LDS pipe). After red32(), every lane of DPP-rows 1,3 (lanes
// 16-31 / 48-63) holds the full 32-lane sum of its half-wave.
template <int CTRL, int RMASK>
__device__ __forceinline__ float dppadd(float v) {
  int p = __builtin_amdgcn_update_dpp(0, __float_as_int(v), CTRL, RMASK, 0xF,
                                      false);   // masked rows: old=0 -> +0
  return v + __int_as_float(p);
}
__device__ __forceinline__ float red32(float v) {
  v = dppadd<0xB1, 0xF>(v);    // quad_perm [1,0,3,2]  : xor 1
  v = dppadd<0x4E, 0xF>(v);    // quad_perm [2,3,0,1]  : xor 2
  v = dppadd<0x141, 0xF>(v);   // row_half_mirror      : pair 4s within 8
  v = dppadd<0x140, 0xF>(v);   // row_mirror           : pair 8s within 16
  v = dppadd<0x142, 0xA>(v);   // row_bcast15 -> rows 1,3 get 32-sums
  return v;
}

__device__ __forceinline__ float2 unpack_gs(unsigned w) {
  return make_float2(
      __half2float(__ushort_as_half((unsigned short)(w & 0xFFFFu))),
      __half2float(__ushort_as_half((unsigned short)(w >> 16))));
}

// ---------------------------------------------------------------------------
// Build the r-tables: cell c holds St (f32) and packed {Sg,Sl} (2xf16) at
// r = c/TSCALE. f16 rel err ~5e-4 << the ~2.5e-3 nearest-cell quantization
// already present, so the packing is below the established noise floor.
__global__ __launch_bounds__(256)
void tfl_tabgen(const float* __restrict__ p1, const float* __restrict__ pb1,
                const float* __restrict__ p2, float* __restrict__ stTab,
                unsigned* __restrict__ gsTab) {
  const int c = blockIdx.x * 256 + threadIdx.x;
  if (c >= NCELL) return;
  const float r = (float)c * (RMAX / (float)NCELL);
  float St = 0.f, Sg = 0.f, Sl = 0.f;
  for (int h = 0; h < H_DIM; ++h) {
    float p1h = p1[h], P2h = p2[h];
    float arg = TWO_LOG2E * fmaf(r, p1h, pb1[h]);
    float y = __builtin_amdgcn_exp2f(arg);
    float u = __builtin_amdgcn_rcpf(y + 1.0f);
    float t = fmaf(-2.0f, u, 1.0f);            // tanh
    float dd = fmaf(-u, u, u);                 // sech^2 / 4
    St = fmaf(t, P2h, St);
    Sg = fmaf(dd, 4.0f * p1h * P2h, Sg);       // dPhi
    Sl = fmaf(t * dd, -8.0f * p1h * p1h * P2h, Sl);  // d2Phi
  }
  stTab[c] = St;
  gsTab[c] = (unsigned)__half_as_ushort(__float2half_rn(Sg)) |
             ((unsigned)__half_as_ushort(__float2half_rn(Sl)) << 16);
}

// ---------------------------------------------------------------------------
// Main: 1024 blocks = 32 jobs x 32 rowgroups(16 rows). 512 threads:
// 32 threads per row, each thread owns 16 j's.
// NEW vs round 9: X positions are read from GLOBAL (VMEM pipe) instead of
// an LDS stage — X is 4KB/job, L1/L2-resident, read-once-per-thread in a
// coalesced pattern (upper half-wave broadcasts). This moves ~64 cyc/wave
// of b64 reads off the saturated LDS pipe onto the idle VMEM pipe, and
// frees the 4KB Xs buffer + its staging.
// LDS now carries ONLY the table planes + tiny sred.
// Mode-specialized staging & gathers (E telescoped):
//   DRIFT (l=1..6): stage packed plane (8KB); ONE ds_read_b32 gather/pair.
//   L0    (l==0)  : stage st + packed (16KB); 2 b32 gathers/pair.
//   EMODE (l==7)  : stage st (8KB); 1 b32 gather/pair.
// DPP reductions on the VALU pipe (round 8). No cross-block sync (rounds
// 1/3/5: L2 maintenance storms + f64 CAS contention always lose).
__global__ __launch_bounds__(512)
void tfl_main13(const float* __restrict__ data, const float* __restrict__ tsnap,
                const float* __restrict__ W1, const float* __restrict__ b1,
                const float* __restrict__ w2, const float* __restrict__ stTab,
                const unsigned* __restrict__ gsTab,
                double* __restrict__ partials) {
  const int jb = blockIdx.x >> 5;
  const int rb = blockIdx.x & 31;
  const bool emode = (jb >= N_STEPS);
  const int m = emode ? (jb - N_STEPS) : jb / (L_DIM - 1);
  const int l = emode ? (L_DIM - 1) : jb % (L_DIM - 1);
  const bool l0 = (!emode && l == 0);
  const float2* __restrict__ X2 =
      (const float2*)(data + (size_t)(m * L_DIM + l) * (N_PART * 2));

  __shared__ __align__(16) float sPl[NCELL * 2];    // 16 KB (mode-dep views)
  __shared__ double sred[8][3];

  const int tid = threadIdx.x;
  if (l0) {
    ((float4*)sPl)[tid] = ((const float4*)stTab)[tid];         // st: 8 KB
    ((float4*)sPl)[512 + tid] = ((const float4*)gsTab)[tid];   // gs: 8 KB
  } else if (!emode) {
    ((float4*)sPl)[tid] = ((const float4*)gsTab)[tid];         // gs only
  } else {
    ((float4*)sPl)[tid] = ((const float4*)stTab)[tid];         // st only
  }
  __syncthreads();

  const float* sSt = sPl;                                      // L0 / EMODE
  const unsigned* sGsU = (const unsigned*)(sPl + (l0 ? NCELL : 0));

  const int wv = tid >> 6;
  const int ln = tid & 63;
  const int g = ln & 31;               // j-group id / h id (32 lanes per row)
  const int row = rb * 16 + (tid >> 5);
  const float2 xi = X2[row];
  const float xi0 = xi.x, xi1 = xi.y;
  const float invN = 1.0f / N_PART;
  const float invN2 = invN * invN;
  const float rs0 = __builtin_amdgcn_rsqf(1e-20f);

  float bJd = 0.f, bLap = 0.f, bE = 0.f;       // this wave's 2-row partials

  if (!emode && !l0) {
    // ------- DRIFT: ONE b32 packed gather, no St, no Vi, 3-var reduce -----
    float aGx = 0.f, aGy = 0.f, aLw = 0.f;
#pragma unroll 4
    for (int kk = 0; kk < 16; ++kk) {
      const int j = g + 32 * kk;
      float2 xj = X2[j];                        // VMEM (L1/L2 hit)
      float dx = xi0 - xj.x, dy = xi1 - xj.y;
      float sq = fmaxf(fmaf(dx, dx, dy * dy), 1e-20f);
      float rs = __builtin_amdgcn_rsqf(sq);
      float r = sq * rs;
      int ki = (int)fmaf(r, TSCALE, 0.5f);
      ki = min(ki, NCELL - 1);
      float2 gs = unpack_gs(sGsU[ki]);
      float tg = gs.x * rs;                     // dPhi / r
      aGx = fmaf(dx, tg, aGx);
      aGy = fmaf(dy, tg, aGy);
      aLw += tg + gs.y;                         // d2Phi + dPhi/r (incl diag)
    }
    float gVx, gVy, lapV;
    {
      float w10 = W1[g], w11 = W1[H_DIM + g], w2h = w2[g];
      float arg = TWO_LOG2E * fmaf(xi0, w10, fmaf(xi1, w11, b1[g]));
      float y = __builtin_amdgcn_exp2f(arg);
      float u = __builtin_amdgcn_rcpf(y + 1.0f);
      float t = fmaf(-2.0f, u, 1.0f);
      float dd = fmaf(-u, u, u);
      float g4 = 4.0f * dd * w2h;
      gVx = g4 * w10;
      gVy = g4 * w11;
      lapV = t * dd * (-8.0f * w2h) * fmaf(w10, w10, w11 * w11);
    }
    float gx = red32(fmaf(aGx, invN, gVx));
    float gy = red32(fmaf(aGy, invN, gVy));
    float lw = red32(fmaf(aLw, invN, lapV));
    float2 gs0 = unpack_gs(sGsU[0]);            // same f16 values loop added
    lw -= fmaf(gs0.x, rs0, gs0.y) * invN;       // remove diagonal lap term
    float cJd = fmaf(gx, gx, gy * gy);
    cJd += __shfl_xor(cJd, 32);
    lw += __shfl_xor(lw, 32);
    bJd = cJd; bLap = lw;
  } else if (l0) {
    // ------- L0: full path (drift + lap + E), 2 b32 gathers ---------------
    float aSt = 0.f, aGx = 0.f, aGy = 0.f, aLw = 0.f;
#pragma unroll 4
    for (int kk = 0; kk < 16; ++kk) {
      const int j = g + 32 * kk;
      float2 xj = X2[j];
      float dx = xi0 - xj.x, dy = xi1 - xj.y;
      float sq = fmaxf(fmaf(dx, dx, dy * dy), 1e-20f);
      float rs = __builtin_amdgcn_rsqf(sq);
      float r = sq * rs;
      int ki = (int)fmaf(r, TSCALE, 0.5f);
      ki = min(ki, NCELL - 1);
      float Stv = sSt[ki];
      float2 gs = unpack_gs(sGsU[ki]);
      float tg = gs.x * rs;
      aSt += Stv;
      aGx = fmaf(dx, tg, aGx);
      aGy = fmaf(dy, tg, aGy);
      aLw += tg + gs.y;
    }
    float Vi, gVx, gVy, lapV;
    {
      float w10 = W1[g], w11 = W1[H_DIM + g], w2h = w2[g];
      float arg = TWO_LOG2E * fmaf(xi0, w10, fmaf(xi1, w11, b1[g]));
      float y = __builtin_amdgcn_exp2f(arg);
      float u = __builtin_amdgcn_rcpf(y + 1.0f);
      float t = fmaf(-2.0f, u, 1.0f);
      float dd = fmaf(-u, u, u);
      Vi = t * w2h;
      float g4 = 4.0f * dd * w2h;
      gVx = g4 * w10;
      gVy = g4 * w11;
      lapV = t * dd * (-8.0f * w2h) * fmaf(w10, w10, w11 * w11);
    }
    float eA = red32(fmaf(aSt, invN2, Vi * invN));
    float gx = red32(fmaf(aGx, invN, gVx));
    float gy = red32(fmaf(aGy, invN, gVy));
    float lw = red32(fmaf(aLw, invN, lapV));
    float2 gs0 = unpack_gs(sGsU[0]);
    eA -= sSt[0] * invN2;
    lw -= fmaf(gs0.x, rs0, gs0.y) * invN;
    float cJd = fmaf(gx, gx, gy * gy);
    cJd += __shfl_xor(cJd, 32);
    lw += __shfl_xor(lw, 32);
    eA += __shfl_xor(eA, 32);
    bJd = cJd; bLap = lw; bE = eA;
  } else {
    // ------- EMODE: st plane, 1 b32 gather, 1-var reduce ------------------
    float aSt = 0.f;
#pragma unroll 4
    for (int kk = 0; kk < 16; ++kk) {
      const int j = g + 32 * kk;
      float2 xj = X2[j];
      float dx = xi0 - xj.x, dy = xi1 - xj.y;
      float sq = fmaxf(fmaf(dx, dx, dy * dy), 1e-20f);
      float rs = __builtin_amdgcn_rsqf(sq);
      float r = sq * rs;
      int ki = (int)fmaf(r, TSCALE, 0.5f);
      ki = min(ki, NCELL - 1);
      aSt += sSt[ki];
    }
    float Vi;
    {
      float w10 = W1[g], w11 = W1[H_DIM + g], w2h = w2[g];
      float arg = TWO_LOG2E * fmaf(xi0, w10, fmaf(xi1, w11, b1[g]));
      float y = __builtin_amdgcn_exp2f(arg);
      float u = __builtin_amdgcn_rcpf(y + 1.0f);
      float t = fmaf(-2.0f, u, 1.0f);
      Vi = t * w2h;
    }
    float eA = red32(fmaf(aSt, invN2, Vi * invN));
    eA -= sSt[0] * invN2;                       // remove diagonal Phi term
    eA += __shfl_xor(eA, 32);
    bE = eA;
  }

  // ----- per-wave partials -> block partial -> global store -----
  // (32-sums live in DPP-rows 1,3; after the xor-32 combine, lane 16 holds
  //  the wave total)
  if (ln == 16) { sred[wv][0] = bJd; sred[wv][1] = bLap; sred[wv][2] = bE; }
  __syncthreads();
  if (tid == 0) {
    double sJd = 0, sLap = 0, sE = 0;
    for (int w = 0; w < 8; ++w) {
      sJd += sred[w][0]; sLap += sred[w][1]; sE += sred[w][2];
    }
    const double dN = 1.0 / N_PART;
    double j0 = 0.0, j1 = 0.0, j2 = 0.0;
    if (emode) {
      j2 = sE;                                  // +E(m, L-1) telescoped
    } else {
      double dt = (double)(tsnap[l + 1] - tsnap[l]);
      j0 = dt * dN * sJd;                       // J_diss partial
      j1 = dt * 0.01 * dN * sLap;               // J_diff partial
      if (l == 0) j2 = -sE;                     // -E(m, 0) telescoped
    }
    partials[(size_t)blockIdx.x * 3 + 0] = j0;
    partials[(size_t)blockIdx.x * 3 + 1] = j1;
    partials[(size_t)blockIdx.x * 3 + 2] = j2;
  }
}

// ---------------------------------------------------------------------------
// 1 block, 512 threads: each thread sums 2 partial triplets, then a 6-step
// 64-lane shuffle reduce + 8-wave LDS combine (one barrier).
__global__ __launch_bounds__(512)
void tfl_finalize(const double* __restrict__ partials, float* __restrict__ out) {
  __shared__ double sred[8][3];
  const int tid = threadIdx.x;
  const int wv = tid >> 6;
  const int ln = tid & 63;
  const double* pa = partials + (size_t)tid * 3;
  const double* pb = partials + (size_t)(tid + 512) * 3;
  double t0 = pa[0] + pb[0];
  double t1 = pa[1] + pb[1];
  double t2 = pa[2] + pb[2];
#pragma unroll
  for (int sh = 1; sh < 64; sh <<= 1) {
    t0 += __shfl_xor(t0, sh);
    t1 += __shfl_xor(t1, sh);
    t2 += __shfl_xor(t2, sh);
  }
  if (ln == 0) { sred[wv][0] = t0; sred[wv][1] = t1; sred[wv][2] = t2; }
  __syncthreads();
  if (tid == 0) {
    double s0 = 0, s1 = 0, s2 = 0;
    for (int w = 0; w < 8; ++w) {
      s0 += sred[w][0]; s1 += sred[w][1]; s2 += sred[w][2];
    }
    double r = (s0 + s1 - 2.0 * s2) / (double)N_STEPS;
    out[0] = (float)(r * r);
  }
}

// ---------------------------------------------------------------------------
extern "C" void kernel_launch(void* const* d_in, const int* in_sizes, int n_in,
                              void* d_out, int out_size, void* d_ws, size_t ws_size,
                              hipStream_t stream) {
  (void)in_sizes; (void)n_in; (void)out_size; (void)ws_size;
  const float* data  = (const float*)d_in[0];
  const float* tsnap = (const float*)d_in[1];
  const float* W1    = (const float*)d_in[2];
  const float* b1    = (const float*)d_in[3];
  const float* w2    = (const float*)d_in[4];
  // d_in[5] = b2 (cancels in telescoped dE)
  const float* p1    = (const float*)d_in[6];
  const float* pb1   = (const float*)d_in[7];
  const float* p2    = (const float*)d_in[8];
  // d_in[9] = pb2 (cancels in telescoped dE)
  float* stTab = (float*)((char*)d_ws + ST_OFF);
  unsigned* gsTab = (unsigned*)((char*)d_ws + GS_OFF);
  double* partials = (double*)((char*)d_ws + PART_OFF);
  float* out = (float*)d_out;

  hipLaunchKernelGGL(tfl_tabgen, dim3(NCELL / 256), dim3(256), 0, stream,
                     p1, pb1, p2, stTab, gsTab);
  hipLaunchKernelGGL(tfl_main13, dim3(NBLK), dim3(512), 0, stream,
                     data, tsnap, W1, b1, w2, stTab, gsTab, partials);
  hipLaunchKernelGGL(tfl_finalize, dim3(1), dim3(512), 0, stream, partials, out);
}

// Round 11
// 18.504 us; speedup vs baseline: 1.0253x; 1.0253x over previous
//
#include <hip/hip_runtime.h>
#include <hip/hip_fp16.h>

#define N_PART 512
#define H_DIM 32
#define M_DIM 4
#define L_DIM 8
#define N_STEPS (M_DIM * (L_DIM - 1))   // 28
#define N_JOBS (N_STEPS + M_DIM)        // 32
#define NBLK (N_JOBS * 32)              // 1024 (32 rowgroups of 16 rows)
#define NCELL 2048
#define RMAX 10.0f
#define TSCALE ((float)NCELL / RMAX)    // 204.8
#define TWO_LOG2E 2.8853900817779268f

// ws layout (two 4B-stride planes -> full 32-bank spread on random gathers;
// round-3 lesson: 8B-stride pairs alias to even banks):
//  [0, 8KB)     stTab  float[2048]     St (f32 — feeds telescoped E)
//  [8K, 16KB)   gsTab  uint[2048]      packed {Sg,Sl} as 2xf16
//  [16K, 40KB)  partials double[1024][3]
#define ST_OFF 0
#define GS_OFF (NCELL * 4)
#define PART_OFF (NCELL * 8)

// ---------------------------------------------------------------------------
// DPP-based 32-lane sum reduction (round-8 win: reduce on VALU pipe, not the
// contended LDS pipe). After red32(), every lane of DPP-rows 1,3 (lanes
// 16-31 / 48-63) holds the full 32-lane sum of its half-wave.
template <int CTRL, int RMASK>
__device__ __forceinline__ float dppadd(float v) {
  int p = __builtin_amdgcn_update_dpp(0, __float_as_int(v), CTRL, RMASK, 0xF,
                                      false);   // masked rows: old=0 -> +0
  return v + __int_as_float(p);
}
__device__ __forceinline__ float red32(float v) {
  v = dppadd<0xB1, 0xF>(v);    // quad_perm [1,0,3,2]  : xor 1
  v = dppadd<0x4E, 0xF>(v);    // quad_perm [2,3,0,1]  : xor 2
  v = dppadd<0x141, 0xF>(v);   // row_half_mirror      : pair 4s within 8
  v = dppadd<0x140, 0xF>(v);   // row_mirror           : pair 8s within 16
  v = dppadd<0x142, 0xA>(v);   // row_bcast15 -> rows 1,3 get 32-sums
  return v;
}

__device__ __forceinline__ float2 unpack_gs(unsigned w) {
  return make_float2(
      __half2float(__ushort_as_half((unsigned short)(w & 0xFFFFu))),
      __half2float(__ushort_as_half((unsigned short)(w >> 16))));
}

// ---------------------------------------------------------------------------
// Build the r-tables: cell c holds St (f32) and packed {Sg,Sl} (2xf16) at
// r = c/TSCALE. f16 rel err ~5e-4 << the ~2.5e-3 nearest-cell quantization
// already present, so the packing is below the established noise floor.
__global__ __launch_bounds__(256)
void tfl_tabgen(const float* __restrict__ p1, const float* __restrict__ pb1,
                const float* __restrict__ p2, float* __restrict__ stTab,
                unsigned* __restrict__ gsTab) {
  const int c = blockIdx.x * 256 + threadIdx.x;
  if (c >= NCELL) return;
  const float r = (float)c * (RMAX / (float)NCELL);
  float St = 0.f, Sg = 0.f, Sl = 0.f;
  for (int h = 0; h < H_DIM; ++h) {
    float p1h = p1[h], P2h = p2[h];
    float arg = TWO_LOG2E * fmaf(r, p1h, pb1[h]);
    float y = __builtin_amdgcn_exp2f(arg);
    float u = __builtin_amdgcn_rcpf(y + 1.0f);
    float t = fmaf(-2.0f, u, 1.0f);            // tanh
    float dd = fmaf(-u, u, u);                 // sech^2 / 4
    St = fmaf(t, P2h, St);
    Sg = fmaf(dd, 4.0f * p1h * P2h, Sg);       // dPhi
    Sl = fmaf(t * dd, -8.0f * p1h * p1h * P2h, Sl);  // d2Phi
  }
  stTab[c] = St;
  gsTab[c] = (unsigned)__half_as_ushort(__float2half_rn(Sg)) |
             ((unsigned)__half_as_ushort(__float2half_rn(Sl)) << 16);
}

// ---------------------------------------------------------------------------
// Main: 1024 blocks = 32 jobs x 32 rowgroups(16 rows). 512 threads:
// 32 threads per row, each thread owns 16 j's.
// Mode-specialized staging & gathers (E telescoped):
//   DRIFT (l=1..6): stage packed plane (8KB); ONE ds_read_b32 gather/pair.
//   L0    (l==0)  : stage st + packed (16KB); 2 b32 gathers/pair.
//   EMODE (l==7)  : stage st (8KB); 1 b32 gather/pair.
// X staged in LDS (round-10 lesson: global X reads add unhidden VMEM
// latency; the LDS reads ride free behind the gather traffic).
// DPP reductions on the VALU pipe (round 8). No cross-block sync (rounds
// 1/3/5: L2 maintenance storms + f64 CAS contention always lose).
__global__ __launch_bounds__(512)
void tfl_main12(const float* __restrict__ data, const float* __restrict__ tsnap,
                const float* __restrict__ W1, const float* __restrict__ b1,
                const float* __restrict__ w2, const float* __restrict__ stTab,
                const unsigned* __restrict__ gsTab,
                double* __restrict__ partials) {
  const int jb = blockIdx.x >> 5;
  const int rb = blockIdx.x & 31;
  const bool emode = (jb >= N_STEPS);
  const int m = emode ? (jb - N_STEPS) : jb / (L_DIM - 1);
  const int l = emode ? (L_DIM - 1) : jb % (L_DIM - 1);
  const bool l0 = (!emode && l == 0);
  const float* X = data + (size_t)(m * L_DIM + l) * (N_PART * 2);

  __shared__ __align__(16) float sPl[NCELL * 2];    // 16 KB (mode-dep views)
  __shared__ __align__(16) float Xs[N_PART * 2];    // 4 KB
  __shared__ double sred[8][3];

  const int tid = threadIdx.x;
  if (tid < 256) ((float4*)Xs)[tid] = ((const float4*)X)[tid];
  if (l0) {
    ((float4*)sPl)[tid] = ((const float4*)stTab)[tid];         // st: 8 KB
    ((float4*)sPl)[512 + tid] = ((const float4*)gsTab)[tid];   // gs: 8 KB
  } else if (!emode) {
    ((float4*)sPl)[tid] = ((const float4*)gsTab)[tid];         // gs only
  } else {
    ((float4*)sPl)[tid] = ((const float4*)stTab)[tid];         // st only
  }
  __syncthreads();

  const float* sSt = sPl;                                      // L0 / EMODE
  const unsigned* sGsU = (const unsigned*)(sPl + (l0 ? NCELL : 0));

  const int wv = tid >> 6;
  const int ln = tid & 63;
  const int g = ln & 31;               // j-group id / h id (32 lanes per row)
  const int row = rb * 16 + (tid >> 5);
  const float xi0 = Xs[2 * row], xi1 = Xs[2 * row + 1];
  const float invN = 1.0f / N_PART;
  const float invN2 = invN * invN;
  const float rs0 = __builtin_amdgcn_rsqf(1e-20f);
  const float2* Xs2 = (const float2*)Xs;

  float bJd = 0.f, bLap = 0.f, bE = 0.f;       // this wave's 2-row partials

  if (!emode && !l0) {
    // ------- DRIFT: ONE b32 packed gather, no St, no Vi, 3-var reduce -----
    float aGx = 0.f, aGy = 0.f, aLw = 0.f;
#pragma unroll 4
    for (int kk = 0; kk < 16; ++kk) {
      const int j = g + 32 * kk;
      float2 xj = Xs2[j];
      float dx = xi0 - xj.x, dy = xi1 - xj.y;
      float sq = fmaxf(fmaf(dx, dx, dy * dy), 1e-20f);
      float rs = __builtin_amdgcn_rsqf(sq);
      float r = sq * rs;
      int ki = (int)fmaf(r, TSCALE, 0.5f);
      ki = min(ki, NCELL - 1);
      float2 gs = unpack_gs(sGsU[ki]);
      float tg = gs.x * rs;                     // dPhi / r
      aGx = fmaf(dx, tg, aGx);
      aGy = fmaf(dy, tg, aGy);
      aLw += tg + gs.y;                         // d2Phi + dPhi/r (incl diag)
    }
    float gVx, gVy, lapV;
    {
      float w10 = W1[g], w11 = W1[H_DIM + g], w2h = w2[g];
      float arg = TWO_LOG2E * fmaf(xi0, w10, fmaf(xi1, w11, b1[g]));
      float y = __builtin_amdgcn_exp2f(arg);
      float u = __builtin_amdgcn_rcpf(y + 1.0f);
      float t = fmaf(-2.0f, u, 1.0f);
      float dd = fmaf(-u, u, u);
      float g4 = 4.0f * dd * w2h;
      gVx = g4 * w10;
      gVy = g4 * w11;
      lapV = t * dd * (-8.0f * w2h) * fmaf(w10, w10, w11 * w11);
    }
    float gx = red32(fmaf(aGx, invN, gVx));
    float gy = red32(fmaf(aGy, invN, gVy));
    float lw = red32(fmaf(aLw, invN, lapV));
    float2 gs0 = unpack_gs(sGsU[0]);            // same f16 values loop added
    lw -= fmaf(gs0.x, rs0, gs0.y) * invN;       // remove diagonal lap term
    float cJd = fmaf(gx, gx, gy * gy);
    cJd += __shfl_xor(cJd, 32);
    lw += __shfl_xor(lw, 32);
    bJd = cJd; bLap = lw;
  } else if (l0) {
    // ------- L0: full path (drift + lap + E), 2 b32 gathers ---------------
    float aSt = 0.f, aGx = 0.f, aGy = 0.f, aLw = 0.f;
#pragma unroll 4
    for (int kk = 0; kk < 16; ++kk) {
      const int j = g + 32 * kk;
      float2 xj = Xs2[j];
      float dx = xi0 - xj.x, dy = xi1 - xj.y;
      float sq = fmaxf(fmaf(dx, dx, dy * dy), 1e-20f);
      float rs = __builtin_amdgcn_rsqf(sq);
      float r = sq * rs;
      int ki = (int)fmaf(r, TSCALE, 0.5f);
      ki = min(ki, NCELL - 1);
      float Stv = sSt[ki];
      float2 gs = unpack_gs(sGsU[ki]);
      float tg = gs.x * rs;
      aSt += Stv;
      aGx = fmaf(dx, tg, aGx);
      aGy = fmaf(dy, tg, aGy);
      aLw += tg + gs.y;
    }
    float Vi, gVx, gVy, lapV;
    {
      float w10 = W1[g], w11 = W1[H_DIM + g], w2h = w2[g];
      float arg = TWO_LOG2E * fmaf(xi0, w10, fmaf(xi1, w11, b1[g]));
      float y = __builtin_amdgcn_exp2f(arg);
      float u = __builtin_amdgcn_rcpf(y + 1.0f);
      float t = fmaf(-2.0f, u, 1.0f);
      float dd = fmaf(-u, u, u);
      Vi = t * w2h;
      float g4 = 4.0f * dd * w2h;
      gVx = g4 * w10;
      gVy = g4 * w11;
      lapV = t * dd * (-8.0f * w2h) * fmaf(w10, w10, w11 * w11);
    }
    float eA = red32(fmaf(aSt, invN2, Vi * invN));
    float gx = red32(fmaf(aGx, invN, gVx));
    float gy = red32(fmaf(aGy, invN, gVy));
    float lw = red32(fmaf(aLw, invN, lapV));
    float2 gs0 = unpack_gs(sGsU[0]);
    eA -= sSt[0] * invN2;
    lw -= fmaf(gs0.x, rs0, gs0.y) * invN;
    float cJd = fmaf(gx, gx, gy * gy);
    cJd += __shfl_xor(cJd, 32);
    lw += __shfl_xor(lw, 32);
    eA += __shfl_xor(eA, 32);
    bJd = cJd; bLap = lw; bE = eA;
  } else {
    // ------- EMODE: st plane, 1 b32 gather, 1-var reduce ------------------
    float aSt = 0.f;
#pragma unroll 4
    for (int kk = 0; kk < 16; ++kk) {
      const int j = g + 32 * kk;
      float2 xj = Xs2[j];
      float dx = xi0 - xj.x, dy = xi1 - xj.y;
      float sq = fmaxf(fmaf(dx, dx, dy * dy), 1e-20f);
      float rs = __builtin_amdgcn_rsqf(sq);
      float r = sq * rs;
      int ki = (int)fmaf(r, TSCALE, 0.5f);
      ki = min(ki, NCELL - 1);
      aSt += sSt[ki];
    }
    float Vi;
    {
      float w10 = W1[g], w11 = W1[H_DIM + g], w2h = w2[g];
      float arg = TWO_LOG2E * fmaf(xi0, w10, fmaf(xi1, w11, b1[g]));
      float y = __builtin_amdgcn_exp2f(arg);
      float u = __builtin_amdgcn_rcpf(y + 1.0f);
      float t = fmaf(-2.0f, u, 1.0f);
      Vi = t * w2h;
    }
    float eA = red32(fmaf(aSt, invN2, Vi * invN));
    eA -= sSt[0] * invN2;                       // remove diagonal Phi term
    eA += __shfl_xor(eA, 32);
    bE = eA;
  }

  // ----- per-wave partials -> block partial -> global store -----
  // (32-sums live in DPP-rows 1,3; after the xor-32 combine, lane 16 holds
  //  the wave total)
  if (ln == 16) { sred[wv][0] = bJd; sred[wv][1] = bLap; sred[wv][2] = bE; }
  __syncthreads();
  if (tid == 0) {
    double sJd = 0, sLap = 0, sE = 0;
    for (int w = 0; w < 8; ++w) {
      sJd += sred[w][0]; sLap += sred[w][1]; sE += sred[w][2];
    }
    const double dN = 1.0 / N_PART;
    double j0 = 0.0, j1 = 0.0, j2 = 0.0;
    if (emode) {
      j2 = sE;                                  // +E(m, L-1) telescoped
    } else {
      double dt = (double)(tsnap[l + 1] - tsnap[l]);
      j0 = dt * dN * sJd;                       // J_diss partial
      j1 = dt * 0.01 * dN * sLap;               // J_diff partial
      if (l == 0) j2 = -sE;                     // -E(m, 0) telescoped
    }
    partials[(size_t)blockIdx.x * 3 + 0] = j0;
    partials[(size_t)blockIdx.x * 3 + 1] = j1;
    partials[(size_t)blockIdx.x * 3 + 2] = j2;
  }
}

// ---------------------------------------------------------------------------
// 1 block, 512 threads: each thread sums 2 partial triplets, then a 6-step
// 64-lane shuffle reduce + 8-wave LDS combine (one barrier).
__global__ __launch_bounds__(512)
void tfl_finalize(const double* __restrict__ partials, float* __restrict__ out) {
  __shared__ double sred[8][3];
  const int tid = threadIdx.x;
  const int wv = tid >> 6;
  const int ln = tid & 63;
  const double* pa = partials + (size_t)tid * 3;
  const double* pb = partials + (size_t)(tid + 512) * 3;
  double t0 = pa[0] + pb[0];
  double t1 = pa[1] + pb[1];
  double t2 = pa[2] + pb[2];
#pragma unroll
  for (int sh = 1; sh < 64; sh <<= 1) {
    t0 += __shfl_xor(t0, sh);
    t1 += __shfl_xor(t1, sh);
    t2 += __shfl_xor(t2, sh);
  }
  if (ln == 0) { sred[wv][0] = t0; sred[wv][1] = t1; sred[wv][2] = t2; }
  __syncthreads();
  if (tid == 0) {
    double s0 = 0, s1 = 0, s2 = 0;
    for (int w = 0; w < 8; ++w) {
      s0 += sred[w][0]; s1 += sred[w][1]; s2 += sred[w][2];
    }
    double r = (s0 + s1 - 2.0 * s2) / (double)N_STEPS;
    out[0] = (float)(r * r);
  }
}

// ---------------------------------------------------------------------------
extern "C" void kernel_launch(void* const* d_in, const int* in_sizes, int n_in,
                              void* d_out, int out_size, void* d_ws, size_t ws_size,
                              hipStream_t stream) {
  (void)in_sizes; (void)n_in; (void)out_size; (void)ws_size;
  const float* data  = (const float*)d_in[0];
  const float* tsnap = (const float*)d_in[1];
  const float* W1    = (const float*)d_in[2];
  const float* b1    = (const float*)d_in[3];
  const float* w2    = (const float*)d_in[4];
  // d_in[5] = b2 (cancels in telescoped dE)
  const float* p1    = (const float*)d_in[6];
  const float* pb1   = (const float*)d_in[7];
  const float* p2    = (const float*)d_in[8];
  // d_in[9] = pb2 (cancels in telescoped dE)
  float* stTab = (float*)((char*)d_ws + ST_OFF);
  unsigned* gsTab = (unsigned*)((char*)d_ws + GS_OFF);
  double* partials = (double*)((char*)d_ws + PART_OFF);
  float* out = (float*)d_out;

  hipLaunchKernelGGL(tfl_tabgen, dim3(NCELL / 256), dim3(256), 0, stream,
                     p1, pb1, p2, stTab, gsTab);
  hipLaunchKernelGGL(tfl_main12, dim3(NBLK), dim3(512), 0, stream,
                     data, tsnap, W1, b1, w2, stTab, gsTab, partials);
  hipLaunchKernelGGL(tfl_finalize, dim3(1), dim3(512), 0, stream, partials, out);
}